// Round 1
// baseline (212.544 us; speedup 1.0000x reference)
//
#include <hip/hip_runtime.h>
#include <stdint.h>

typedef unsigned short u16;
typedef __attribute__((ext_vector_type(8))) __bf16 bf16x8;
typedef __attribute__((ext_vector_type(4))) float f32x4;

#define Dn 512
#define Mn 16384  // T*B rows

// ---------- helpers ----------

__device__ __forceinline__ u16 f2bf(float f) {
  unsigned u = __float_as_uint(f);
  u += 0x7fffu + ((u >> 16) & 1u);
  return (u16)(u >> 16);
}

__device__ __forceinline__ float bf2f(u16 b) {
  return __uint_as_float(((unsigned)b) << 16);
}

__device__ __forceinline__ void async16(const u16* g, u16* l) {
  // global -> LDS direct copy, 16 B per lane. LDS dest = wave-uniform base + lane*16.
  __builtin_amdgcn_global_load_lds(
      (const __attribute__((address_space(1))) unsigned int*)g,
      (__attribute__((address_space(3))) unsigned int*)l, 16, 0, 0);
}

__device__ __forceinline__ float sigmoidf_(float v) {
  return 1.f / (1.f + __expf(-v));
}

// ---------- merged cast kernel ----------
// blocks 0..8191: y -> yb ; 8192..16383: x -> xb ;
// 16384..17919: 6 weights -> concat layouts:
//   bRZ (1024 x 1024 bf16): rows 0-511 = [Wr | Ur], rows 512-1023 = [Wz | Uz]
//   bG  ( 512 x 1024 bf16): rows 0-511 = [Wg | Ug]
__global__ void cast_all(const float* __restrict__ y, const float* __restrict__ x,
                         const float* w0, const float* w1, const float* w2,
                         const float* w3, const float* w4, const float* w5,
                         u16* __restrict__ yb, u16* __restrict__ xb,
                         u16* __restrict__ bRZ, u16* __restrict__ bG) {
  int b = blockIdx.x;
  const int t = (int)threadIdx.x;
  if (b < 16384) {
    const float* src;
    u16* dst;
    if (b < 8192) { src = y; dst = yb; }
    else          { src = x; dst = xb; b -= 8192; }
    const int i4 = b * 256 + t;
    float4 v = ((const float4*)src)[i4];
    ushort4 o;
    o.x = f2bf(v.x); o.y = f2bf(v.y); o.z = f2bf(v.z); o.w = f2bf(v.w);
    ((ushort4*)dst)[i4] = o;
    return;
  }
  b -= 16384;
  const int wi = b >> 8;  // 0..5 : Wr,Ur,Wz,Uz,Wg,Ug
  const int bb = b & 255;
  const float* src = wi == 0 ? w0 : wi == 1 ? w1 : wi == 2 ? w2
                   : wi == 3 ? w3 : wi == 4 ? w4 : w5;
  const int i4 = bb * 256 + t;        // float4 index within 512x512 weight
  const int e  = i4 >> 7;             // output row 0..511
  const int c4 = i4 & 127;            // float4 col within 512
  float4 v = ((const float4*)src)[i4];
  ushort4 o;
  o.x = f2bf(v.x); o.y = f2bf(v.y); o.z = f2bf(v.z); o.w = f2bf(v.w);
  ushort4* base = (wi >= 4) ? (ushort4*)bG : (ushort4*)bRZ;
  const int row = e + ((wi == 2 || wi == 3) ? 512 : 0);
  const int off = row * 256 + c4 + ((wi & 1) ? 128 : 0);  // 256 ushort4 per 1024-col row
  base[off] = o;
}

// ---------- GEMM 1 (pipelined): C = [y|x] @ bRZ^T  (M=16384, N=1024, K=1024) ----------
// 256x256 tile, BK=32, 512 threads (8 waves as 2Mx4N, wave tile 128x64).
// 4 LDS slots x 32KB (A 16KB + B 16KB) = 128KB -> 1 block/CU.
// Counted-vmcnt pipeline (T3+T4): depth-3/4 prefetch, raw s_barrier + manual waits,
// never vmcnt(0) in steady state. Ledger (4 global_load_lds per K-tile per wave):
//   prologue stages ktiles 0..3 (16 in flight).
//   iter t: vmcnt(12) -> ktile t landed, {t+1,t+2,t+3} in flight; bar;
//           12x ds_read_b128; lgkmcnt(0); bar (slot t&3 now reusable);
//           STAGE(t+4) into slot t&3; 32x MFMA (setprio 1).
//   tail waits: t=29 -> vmcnt(8), t=30 -> vmcnt(4), t=31 -> vmcnt(0).
// LDS layout per slot: A[256][32] then B[256][32], row = 64B = 4 chunks of 16B.
// Swizzle: phys chunk = logical ^ ((row>>1)&3). Banks: 16*(row&1) + 4*phys ->
// 16 rows x fixed quad hit 8 bank-quads 2-way each (2-way = free).
// Staged via pre-swizzled global source col (both-sides-or-neither rule).
__global__ __launch_bounds__(512, 2) void gemm_rz2(
    const u16* __restrict__ yb, const u16* __restrict__ xb,
    const u16* __restrict__ bRZ, const float* __restrict__ bg,
    u16* __restrict__ rxb, u16* __restrict__ zb) {
  __shared__ u16 smem[65536];  // 4 slots x 16384 u16 (32KB)

  const int tid = threadIdx.x;
  const int lane = tid & 63;
  const int wave = tid >> 6;        // 0..7
  const int waveM = wave >> 2;      // 0..1
  const int waveN = wave & 3;       // 0..3
  const int mb = blockIdx.x & 63, nb = blockIdx.x >> 6;  // mb fast -> A-sharers same XCD (64%8==0)
  const int rowStart = mb * 256, colStart = nb * 256;
  const int lm = lane & 15, quad = lane >> 4;
  const int aoff = (quad ^ ((lm >> 1) & 3)) * 8;  // swizzled chunk (u16 units)

  // staging coords: thread covers 16B; 4 threads per 64B row
  const int srow = tid >> 2;                          // 0..127 within an s-group
  const int lc = ((tid & 3) ^ ((srow >> 1) & 3)) * 8; // pre-swizzled source col (u16)
  const int woff = wave * 1024;                       // wave-uniform LDS byte base

  f32x4 acc[8][4] = {};

  auto STAGE = [&](int t) {
    const u16* abase = (t < 16) ? yb : xb;  // A = [y | x] along K
    const int k0 = (t & 15) * 32;
    char* s = (char*)(smem + ((t & 3) << 14));
    async16(abase + (size_t)(rowStart + srow) * 512 + k0 + lc, (u16*)(s + woff));
    async16(abase + (size_t)(rowStart + 128 + srow) * 512 + k0 + lc, (u16*)(s + 8192 + woff));
    async16(bRZ + (size_t)(colStart + srow) * 1024 + t * 32 + lc, (u16*)(s + 16384 + woff));
    async16(bRZ + (size_t)(colStart + 128 + srow) * 1024 + t * 32 + lc, (u16*)(s + 24576 + woff));
  };

  STAGE(0); STAGE(1); STAGE(2); STAGE(3);
  __builtin_amdgcn_sched_barrier(0);  // waits below must not hoist above these issues

  for (int t = 0; t < 32; ++t) {
    if (t < 29)       asm volatile("s_waitcnt vmcnt(12)" ::: "memory");
    else if (t == 29) asm volatile("s_waitcnt vmcnt(8)" ::: "memory");
    else if (t == 30) asm volatile("s_waitcnt vmcnt(4)" ::: "memory");
    else              asm volatile("s_waitcnt vmcnt(0)" ::: "memory");
    __builtin_amdgcn_sched_barrier(0);
    __builtin_amdgcn_s_barrier();  // all waves' ktile-t portions landed

    const u16* sA = smem + ((t & 3) << 14);
    const u16* sB = sA + 8192;
    bf16x8 aa[8], bw[4];
#pragma unroll
    for (int i = 0; i < 8; ++i)
      aa[i] = *(const bf16x8*)(sA + (waveM * 128 + i * 16 + lm) * 32 + aoff);
#pragma unroll
    for (int j = 0; j < 4; ++j)
      bw[j] = *(const bf16x8*)(sB + (waveN * 64 + j * 16 + lm) * 32 + aoff);
    asm volatile("s_waitcnt lgkmcnt(0)" ::: "memory");
    __builtin_amdgcn_sched_barrier(0);  // rule 18: MFMA must not hoist past the wait
    __builtin_amdgcn_s_barrier();       // all waves done reading slot t&3

    if (t < 28) STAGE(t + 4);           // refill slot t&3 (safe: past bar2)
    __builtin_amdgcn_sched_barrier(0);  // loads issue before MFMA; next wait can't hoist above

    __builtin_amdgcn_s_setprio(1);
#pragma unroll
    for (int i = 0; i < 8; ++i)
#pragma unroll
      for (int j = 0; j < 4; ++j)
        acc[i][j] = __builtin_amdgcn_mfma_f32_16x16x32_bf16(aa[i], bw[j], acc[i][j], 0, 0, 0);
    __builtin_amdgcn_s_setprio(0);
  }

  if (colStart < 512) {
    // R half: rx = bf16(sigmoid(acc) * x)
#pragma unroll
    for (int j = 0; j < 4; ++j) {
      const int e = colStart + waveN * 64 + j * 16 + lm;
#pragma unroll
      for (int i = 0; i < 8; ++i) {
        const int m0 = rowStart + waveM * 128 + i * 16 + quad * 4;
#pragma unroll
        for (int rg = 0; rg < 4; ++rg) {
          const size_t idx = (size_t)(m0 + rg) * 512 + e;
          const float r = sigmoidf_(acc[i][j][rg]);
          rxb[idx] = f2bf(r * bf2f(xb[idx]));
        }
      }
    }
  } else {
    // Z half: z = bf16(sigmoid(acc - bg))
#pragma unroll
    for (int j = 0; j < 4; ++j) {
      const int e = colStart - 512 + waveN * 64 + j * 16 + lm;
      const float bgv = bg[e];
#pragma unroll
      for (int i = 0; i < 8; ++i) {
        const int m0 = rowStart + waveM * 128 + i * 16 + quad * 4;
#pragma unroll
        for (int rg = 0; rg < 4; ++rg) {
          const size_t idx = (size_t)(m0 + rg) * 512 + e;
          zb[idx] = f2bf(sigmoidf_(acc[i][j][rg] - bgv));
        }
      }
    }
  }
}

// ---------- GEMM 2: accF = [y|rx] @ bG^T (M=16384, N=512, K=1024) ----------
// Same 128x128/BK=64 structure, grid 512, mb fast (same XCD trick: 128%8==0).
// Epilogue: out = (1-z)x + z*tanh(accF)
__global__ __launch_bounds__(256, 4) void gemm_gu1(
    const u16* __restrict__ yb, const u16* __restrict__ rxb,
    const u16* __restrict__ bG,
    const u16* __restrict__ zb, const u16* __restrict__ xb,
    float* __restrict__ out) {
  __shared__ u16 smem[16384];
  u16* sA = smem;
  u16* sB = smem + 8192;

  const int tid = threadIdx.x;
  const int lane = tid & 63;
  const int wave = tid >> 6;
  const int waveM = wave >> 1, waveN = wave & 1;
  const int mb = blockIdx.x & 127, nb = blockIdx.x >> 7;  // mb fast -> A-sharers same XCD
  const int rowStart = mb * 128, colStart = nb * 128;
  const int wbyte = (tid & 192) * 16;
  const int lm = lane & 15, quad = lane >> 4;

  const int srow = tid >> 3;
  const int scol = (((tid & 7) ^ ((tid >> 3) & 7)) * 8);
  const int lswz = lm & 7;

  f32x4 acc[4][4] = {};

  for (int kq = 0; kq < 16; ++kq) {
    const int half = kq >> 3;
    const int k0 = (kq & 7) * 64;
    const u16* abase = half ? rxb : yb;  // A = [y | rx] along K
#pragma unroll
    for (int s = 0; s < 4; ++s) {
      async16(abase + (size_t)(rowStart + s * 32 + srow) * 512 + k0 + scol,
              (u16*)((char*)sA + s * 4096 + wbyte));
      async16(bG + (size_t)(colStart + s * 32 + srow) * 1024 + kq * 64 + scol,
              (u16*)((char*)sB + s * 4096 + wbyte));
    }
    __syncthreads();

#pragma unroll
    for (int kk = 0; kk < 2; ++kk) {
      bf16x8 aa[4], bw[4];
#pragma unroll
      for (int i = 0; i < 4; ++i)
        aa[i] = *(const bf16x8*)(sA + (waveM * 64 + i * 16 + lm) * 64 +
                                 ((kk * 4 + quad) ^ lswz) * 8);
#pragma unroll
      for (int j = 0; j < 4; ++j)
        bw[j] = *(const bf16x8*)(sB + (waveN * 64 + j * 16 + lm) * 64 +
                                 ((kk * 4 + quad) ^ lswz) * 8);
#pragma unroll
      for (int i = 0; i < 4; ++i)
#pragma unroll
        for (int j = 0; j < 4; ++j)
          acc[i][j] = __builtin_amdgcn_mfma_f32_16x16x32_bf16(aa[i], bw[j], acc[i][j], 0, 0, 0);
    }
    __syncthreads();
  }

  // epilogue: out = (1-z)x + z*tanh(accF)
#pragma unroll
  for (int j = 0; j < 4; ++j) {
    const int e = colStart + waveN * 64 + j * 16 + lm;
#pragma unroll
    for (int i = 0; i < 4; ++i) {
      const int m0 = rowStart + waveM * 64 + i * 16 + quad * 4;
#pragma unroll
      for (int rg = 0; rg < 4; ++rg) {
        const size_t idx = (size_t)(m0 + rg) * 512 + e;
        const float pre = acc[i][j][rg];
        const float ex = __expf(-2.f * pre);
        const float h = (1.f - ex) / (1.f + ex);  // tanh
        const float z = bf2f(zb[idx]);
        const float xv = bf2f(xb[idx]);
        out[idx] = (1.f - z) * xv + z * h;
      }
    }
  }
}

// ---------- launch ----------
extern "C" void kernel_launch(void* const* d_in, const int* in_sizes, int n_in,
                              void* d_out, int out_size, void* d_ws, size_t ws_size,
                              hipStream_t stream) {
  const float* x  = (const float*)d_in[0];
  const float* y  = (const float*)d_in[1];
  const float* Wr = (const float*)d_in[2];
  const float* Ur = (const float*)d_in[3];
  const float* Wz = (const float*)d_in[4];
  const float* Uz = (const float*)d_in[5];
  const float* Wg = (const float*)d_in[6];
  const float* Ug = (const float*)d_in[7];
  const float* bg = (const float*)d_in[8];
  float* out = (float*)d_out;

  // ws layout (bytes): yb 16M | xb 16M | rxb 16M | zb 16M | bRZ 2M | bG 1M = 67 MB
  char* ws = (char*)d_ws;
  u16* yb  = (u16*)(ws);
  u16* xb  = (u16*)(ws + 16777216);
  u16* rxb = (u16*)(ws + 2 * 16777216);
  u16* zb  = (u16*)(ws + 3 * 16777216);
  u16* bRZ = (u16*)(ws + 4 * 16777216);
  u16* bG  = (u16*)(ws + 4 * 16777216 + 2097152);

  cast_all<<<17920, 256, 0, stream>>>(y, x, Wr, Ur, Wz, Uz, Wg, Ug, yb, xb, bRZ, bG);
  gemm_rz2<<<256, 512, 0, stream>>>(yb, xb, bRZ, bg, rxb, zb);
  gemm_gu1<<<512, 256, 0, stream>>>(yb, rxb, bG, zb, xb, out);
}

// Round 3
// 209.978 us; speedup vs baseline: 1.0122x; 1.0122x over previous
//
#include <hip/hip_runtime.h>
#include <stdint.h>

typedef unsigned short u16;
typedef __attribute__((ext_vector_type(8))) __bf16 bf16x8;
typedef __attribute__((ext_vector_type(4))) float f32x4;

#define Dn 512
#define Mn 16384  // T*B rows
#define NT 16     // K-tiles of 64 in rz3

// ---------- helpers ----------

__device__ __forceinline__ u16 f2bf(float f) {
  unsigned u = __float_as_uint(f);
  u += 0x7fffu + ((u >> 16) & 1u);
  return (u16)(u >> 16);
}

__device__ __forceinline__ float bf2f(u16 b) {
  return __uint_as_float(((unsigned)b) << 16);
}

__device__ __forceinline__ void async16(const u16* g, u16* l) {
  // global -> LDS direct copy, 16 B per lane. LDS dest = wave-uniform base + lane*16.
  __builtin_amdgcn_global_load_lds(
      (const __attribute__((address_space(1))) unsigned int*)g,
      (__attribute__((address_space(3))) unsigned int*)l, 16, 0, 0);
}

__device__ __forceinline__ float sigmoidf_(float v) {
  return 1.f / (1.f + __expf(-v));
}

// ---------- merged cast kernel ----------
// blocks 0..8191: y -> yb ; 8192..16383: x -> xb ;
// 16384..17919: 6 weights -> concat layouts:
//   bRZ (1024 x 1024 bf16): rows 0-511 = [Wr | Ur], rows 512-1023 = [Wz | Uz]
//   bG  ( 512 x 1024 bf16): rows 0-511 = [Wg | Ug]
__global__ void cast_all(const float* __restrict__ y, const float* __restrict__ x,
                         const float* w0, const float* w1, const float* w2,
                         const float* w3, const float* w4, const float* w5,
                         u16* __restrict__ yb, u16* __restrict__ xb,
                         u16* __restrict__ bRZ, u16* __restrict__ bG) {
  int b = blockIdx.x;
  const int t = (int)threadIdx.x;
  if (b < 16384) {
    const float* src;
    u16* dst;
    if (b < 8192) { src = y; dst = yb; }
    else          { src = x; dst = xb; b -= 8192; }
    const int i4 = b * 256 + t;
    float4 v = ((const float4*)src)[i4];
    ushort4 o;
    o.x = f2bf(v.x); o.y = f2bf(v.y); o.z = f2bf(v.z); o.w = f2bf(v.w);
    ((ushort4*)dst)[i4] = o;
    return;
  }
  b -= 16384;
  const int wi = b >> 8;  // 0..5 : Wr,Ur,Wz,Uz,Wg,Ug
  const int bb = b & 255;
  const float* src = wi == 0 ? w0 : wi == 1 ? w1 : wi == 2 ? w2
                   : wi == 3 ? w3 : wi == 4 ? w4 : w5;
  const int i4 = bb * 256 + t;        // float4 index within 512x512 weight
  const int e  = i4 >> 7;             // output row 0..511
  const int c4 = i4 & 127;            // float4 col within 512
  float4 v = ((const float4*)src)[i4];
  ushort4 o;
  o.x = f2bf(v.x); o.y = f2bf(v.y); o.z = f2bf(v.z); o.w = f2bf(v.w);
  ushort4* base = (wi >= 4) ? (ushort4*)bG : (ushort4*)bRZ;
  const int row = e + ((wi == 2 || wi == 3) ? 512 : 0);
  const int off = row * 256 + c4 + ((wi & 1) ? 128 : 0);  // 256 ushort4 per 1024-col row
  base[off] = o;
}

// ---------- GEMM 1 (8-phase): C = [y|x] @ bRZ^T  (M=16384, N=1024, K=1024) ----------
// 256x256 tile, BK=64, 512 thr = 8 waves (2M x 4N), wave tile 128x64. Grid 64x4=256,
// mb fast (64%8==0 -> A-sharers same XCD). LDS = ring of 8 half-tile slots x 16KB =
// 128KB: [buf(t&1)][A0,A1,B0,B1], half-tile = 128 rows x 64 bf16.
// Each wave reads exactly one A-half (wm) and one B-half (wn>>1).
// Per tile t, 4 phases, each: {ds_read subtile ; stage 1 half ; bar ; lgkmcnt(0) ;
// setprio(1) ; 16 MFMA (C-quadrant) ; setprio(0) ; bar}:
//   p0: RD A(i0-3)+B(j0-1) (12 rd) ; stage A0[t+1] ; MMA(i0-3,j0-1)
//   p1: RD B(j2-3)          (4 rd) ; stage A1[t+1] ; MMA(i0-3,j2-3)
//   p2: RD A(i4-7)          (8 rd) ; stage B0[t+2] ; MMA(i4-7,j2-3)
//   p3:                     (0 rd) ; stage B1[t+2] ; MMA(i4-7,j0-1)  [B j0-1 held in regs]
// Race-free ledger: every stage targets a slot whose last ds_read was in a fully
// barriered earlier phase (A-slots last read p2 of prev parity tile; B-slots last
// read p1 of current tile, staged at p2/p3). Counted wait ONCE per tile at end of
// p3: vmcnt(4) (leaves {B0,B1}[t+2] = 2 halves in flight; forces A1[t+1] landed,
// 3-phase lead). vmcnt(0) entering last tile (its stages were the newest issued).
// vmcnt is per-wave -> wait is placed BEFORE the trailing barrier so all waves'
// loads are published. Swizzle: phys chunk = logical ^ (row&7) (0-conflict, proven),
// staged via pre-swizzled global source col (both-sides-or-neither).
__global__ __launch_bounds__(512, 2) void gemm_rz3(
    const u16* __restrict__ yb, const u16* __restrict__ xb,
    const u16* __restrict__ bRZ, const float* __restrict__ bg,
    u16* __restrict__ rxb, u16* __restrict__ zb) {
  __shared__ u16 smem[65536];  // 8 half-slots x 8192 u16 = 128 KB

  const int tid = threadIdx.x;
  const int lane = tid & 63;
  const int wave = tid >> 6;       // 0..7
  const int wm = wave >> 2;        // 0..1
  const int wn = wave & 3;         // 0..3
  const int mb = blockIdx.x & 63, nb = blockIdx.x >> 6;
  const int rowStart = mb * 256, colStart = nb * 256;
  const int lm = lane & 15, quad = lane >> 4;
  const int lswz = lm & 7;

  // staging: one async16 per wave covers 8 rows x 64 cols (1 KB). lane -> row lane>>3,
  // phys chunk lane&7; pre-swizzled logical source chunk = (lane&7)^(lane>>3).
  const int sgrow = lane >> 3;
  const int sgchunk = ((lane & 7) ^ sgrow) * 8;  // u16 col within 64-col row
  const int ldsoff = wave * 512;                 // u16, wave-uniform within half-slot

  f32x4 acc[8][4] = {};
  bf16x8 af[8];   // current i-half: [i2][kk]
  bf16x8 bfr[8];  // all B frags: [j][kk], held across the tile

  const u16* myA;
  const u16* myB;

  // stage half v: tt = v>>2, hid = v&3 (0:B0 1:B1 2:A0 3:A1), kind = (hid+2)&3
  auto STG = [&](int v) {
    const int tt = v >> 2, hid = v & 3;
    if (tt >= NT) return;
    u16* slot = smem + (((tt & 1) * 4 + ((hid + 2) & 3)) * 8192);
    if (hid >= 2) {  // A-half a = hid-2 ; A = [y|x] along K
      const int a = hid - 2;
      const u16* ab = (tt < 8) ? yb : xb;
      const int k0 = (tt & 7) * 64;
#pragma unroll
      for (int s = 0; s < 2; ++s)
        async16(ab + (size_t)(rowStart + a * 128 + s * 64 + wave * 8 + sgrow) * 512 + k0 + sgchunk,
                slot + s * 4096 + ldsoff);
    } else {         // B-half b = hid
      const int b = hid;
#pragma unroll
      for (int s = 0; s < 2; ++s)
        async16(bRZ + (size_t)(colStart + b * 128 + s * 64 + wave * 8 + sgrow) * 1024 + tt * 64 + sgchunk,
                slot + s * 4096 + ldsoff);
    }
  };

  auto RD_A = [&](int ih) {
#pragma unroll
    for (int i2 = 0; i2 < 4; ++i2)
#pragma unroll
      for (int kk = 0; kk < 2; ++kk)
        af[i2 * 2 + kk] = *(const bf16x8*)(myA + (ih * 64 + i2 * 16 + lm) * 64 +
                                           (((kk * 4 + quad) ^ lswz) * 8));
  };
  auto RD_B = [&](int jh) {
#pragma unroll
    for (int j2 = 0; j2 < 2; ++j2)
#pragma unroll
      for (int kk = 0; kk < 2; ++kk)
        bfr[(jh * 2 + j2) * 2 + kk] = *(const bf16x8*)(myB + ((jh * 2 + j2) * 16 + lm) * 64 +
                                                       (((kk * 4 + quad) ^ lswz) * 8));
  };
  auto MMA = [&](int ih, int jh) {
    __builtin_amdgcn_s_setprio(1);
#pragma unroll
    for (int i2 = 0; i2 < 4; ++i2)
#pragma unroll
      for (int j2 = 0; j2 < 2; ++j2)
#pragma unroll
        for (int kk = 0; kk < 2; ++kk)
          acc[ih * 4 + i2][jh * 2 + j2] = __builtin_amdgcn_mfma_f32_16x16x32_bf16(
              af[i2 * 2 + kk], bfr[(jh * 2 + j2) * 2 + kk], acc[ih * 4 + i2][jh * 2 + j2], 0, 0, 0);
    __builtin_amdgcn_s_setprio(0);
  };

  // prologue: stage B0[0],B1[0],A0[0],A1[0],B0[1],B1[1]; force tile0 landed.
#pragma unroll
  for (int v = 0; v < 6; ++v) STG(v);
  __builtin_amdgcn_sched_barrier(0);
  asm volatile("s_waitcnt vmcnt(4)" ::: "memory");
  __builtin_amdgcn_sched_barrier(0);
  __builtin_amdgcn_s_barrier();

#pragma unroll 2
  for (int t = 0; t < NT; ++t) {
    const u16* bufb = smem + (t & 1) * 32768;
    myA = bufb + wm * 8192;
    myB = bufb + (2 + (wn >> 1)) * 8192 + (wn & 1) * 4096;
    const int P = t * 4;

    // ---- phase 0 ----
    RD_A(0); RD_B(0); STG(P + 6);  // stage A0[t+1]
    __builtin_amdgcn_sched_barrier(0);
    __builtin_amdgcn_s_barrier();
    asm volatile("s_waitcnt lgkmcnt(0)" ::: "memory");
    __builtin_amdgcn_sched_barrier(0);
    MMA(0, 0);
    __builtin_amdgcn_sched_barrier(0);
    __builtin_amdgcn_s_barrier();

    // ---- phase 1 ----
    RD_B(1); STG(P + 7);  // stage A1[t+1]
    __builtin_amdgcn_sched_barrier(0);
    __builtin_amdgcn_s_barrier();
    asm volatile("s_waitcnt lgkmcnt(0)" ::: "memory");
    __builtin_amdgcn_sched_barrier(0);
    MMA(0, 1);
    __builtin_amdgcn_sched_barrier(0);
    __builtin_amdgcn_s_barrier();

    // ---- phase 2 ----
    RD_A(1); STG(P + 8);  // stage B0[t+2]
    __builtin_amdgcn_sched_barrier(0);
    __builtin_amdgcn_s_barrier();
    asm volatile("s_waitcnt lgkmcnt(0)" ::: "memory");
    __builtin_amdgcn_sched_barrier(0);
    MMA(1, 1);
    __builtin_amdgcn_sched_barrier(0);
    __builtin_amdgcn_s_barrier();

    // ---- phase 3 ----
    STG(P + 9);  // stage B1[t+2]
    __builtin_amdgcn_sched_barrier(0);
    __builtin_amdgcn_s_barrier();
    MMA(1, 0);  // B j0-1 held in regs since p0
    __builtin_amdgcn_sched_barrier(0);
    if (t < NT - 2)       { asm volatile("s_waitcnt vmcnt(4)" ::: "memory"); }
    else if (t == NT - 2) { asm volatile("s_waitcnt vmcnt(0)" ::: "memory"); }
    __builtin_amdgcn_sched_barrier(0);
    __builtin_amdgcn_s_barrier();
  }

  if (colStart < 512) {
    // R half: rx = bf16(sigmoid(acc) * x)
#pragma unroll
    for (int j = 0; j < 4; ++j) {
      const int e = colStart + wn * 64 + j * 16 + lm;
#pragma unroll
      for (int i = 0; i < 8; ++i) {
        const int m0 = rowStart + wm * 128 + i * 16 + quad * 4;
#pragma unroll
        for (int rg = 0; rg < 4; ++rg) {
          const size_t idx = (size_t)(m0 + rg) * 512 + e;
          const float r = sigmoidf_(acc[i][j][rg]);
          rxb[idx] = f2bf(r * bf2f(xb[idx]));
        }
      }
    }
  } else {
    // Z half: z = bf16(sigmoid(acc - bg))
#pragma unroll
    for (int j = 0; j < 4; ++j) {
      const int e = colStart - 512 + wn * 64 + j * 16 + lm;
      const float bgv = bg[e];
#pragma unroll
      for (int i = 0; i < 8; ++i) {
        const int m0 = rowStart + wm * 128 + i * 16 + quad * 4;
#pragma unroll
        for (int rg = 0; rg < 4; ++rg) {
          const size_t idx = (size_t)(m0 + rg) * 512 + e;
          zb[idx] = f2bf(sigmoidf_(acc[i][j][rg] - bgv));
        }
      }
    }
  }
}

// ---------- GEMM 2: accF = [y|rx] @ bG^T (M=16384, N=512, K=1024) ----------
// Same 128x128/BK=64 structure, grid 512, mb fast (same XCD trick: 128%8==0).
// Epilogue: out = (1-z)x + z*tanh(accF)
__global__ __launch_bounds__(256, 4) void gemm_gu1(
    const u16* __restrict__ yb, const u16* __restrict__ rxb,
    const u16* __restrict__ bG,
    const u16* __restrict__ zb, const u16* __restrict__ xb,
    float* __restrict__ out) {
  __shared__ u16 smem[16384];
  u16* sA = smem;
  u16* sB = smem + 8192;

  const int tid = threadIdx.x;
  const int lane = tid & 63;
  const int wave = tid >> 6;
  const int waveM = wave >> 1, waveN = wave & 1;
  const int mb = blockIdx.x & 127, nb = blockIdx.x >> 7;  // mb fast -> A-sharers same XCD
  const int rowStart = mb * 128, colStart = nb * 128;
  const int wbyte = (tid & 192) * 16;
  const int lm = lane & 15, quad = lane >> 4;

  const int srow = tid >> 3;
  const int scol = (((tid & 7) ^ ((tid >> 3) & 7)) * 8);
  const int lswz = lm & 7;

  f32x4 acc[4][4] = {};

  for (int kq = 0; kq < 16; ++kq) {
    const int half = kq >> 3;
    const int k0 = (kq & 7) * 64;
    const u16* abase = half ? rxb : yb;  // A = [y | rx] along K
#pragma unroll
    for (int s = 0; s < 4; ++s) {
      async16(abase + (size_t)(rowStart + s * 32 + srow) * 512 + k0 + scol,
              (u16*)((char*)sA + s * 4096 + wbyte));
      async16(bG + (size_t)(colStart + s * 32 + srow) * 1024 + kq * 64 + scol,
              (u16*)((char*)sB + s * 4096 + wbyte));
    }
    __syncthreads();

#pragma unroll
    for (int kk = 0; kk < 2; ++kk) {
      bf16x8 aa[4], bw[4];
#pragma unroll
      for (int i = 0; i < 4; ++i)
        aa[i] = *(const bf16x8*)(sA + (waveM * 64 + i * 16 + lm) * 64 +
                                 ((kk * 4 + quad) ^ lswz) * 8);
#pragma unroll
      for (int j = 0; j < 4; ++j)
        bw[j] = *(const bf16x8*)(sB + (waveN * 64 + j * 16 + lm) * 64 +
                                 ((kk * 4 + quad) ^ lswz) * 8);
#pragma unroll
      for (int i = 0; i < 4; ++i)
#pragma unroll
        for (int j = 0; j < 4; ++j)
          acc[i][j] = __builtin_amdgcn_mfma_f32_16x16x32_bf16(aa[i], bw[j], acc[i][j], 0, 0, 0);
    }
    __syncthreads();
  }

  // epilogue: out = (1-z)x + z*tanh(accF)
#pragma unroll
  for (int j = 0; j < 4; ++j) {
    const int e = colStart + waveN * 64 + j * 16 + lm;
#pragma unroll
    for (int i = 0; i < 4; ++i) {
      const int m0 = rowStart + waveM * 64 + i * 16 + quad * 4;
#pragma unroll
      for (int rg = 0; rg < 4; ++rg) {
        const size_t idx = (size_t)(m0 + rg) * 512 + e;
        const float pre = acc[i][j][rg];
        const float ex = __expf(-2.f * pre);
        const float h = (1.f - ex) / (1.f + ex);  // tanh
        const float z = bf2f(zb[idx]);
        const float xv = bf2f(xb[idx]);
        out[idx] = (1.f - z) * xv + z * h;
      }
    }
  }
}

// ---------- launch ----------
extern "C" void kernel_launch(void* const* d_in, const int* in_sizes, int n_in,
                              void* d_out, int out_size, void* d_ws, size_t ws_size,
                              hipStream_t stream) {
  const float* x  = (const float*)d_in[0];
  const float* y  = (const float*)d_in[1];
  const float* Wr = (const float*)d_in[2];
  const float* Ur = (const float*)d_in[3];
  const float* Wz = (const float*)d_in[4];
  const float* Uz = (const float*)d_in[5];
  const float* Wg = (const float*)d_in[6];
  const float* Ug = (const float*)d_in[7];
  const float* bg = (const float*)d_in[8];
  float* out = (float*)d_out;

  // ws layout (bytes): yb 16M | xb 16M | rxb 16M | zb 16M | bRZ 2M | bG 1M = 67 MB
  char* ws = (char*)d_ws;
  u16* yb  = (u16*)(ws);
  u16* xb  = (u16*)(ws + 16777216);
  u16* rxb = (u16*)(ws + 2 * 16777216);
  u16* zb  = (u16*)(ws + 3 * 16777216);
  u16* bRZ = (u16*)(ws + 4 * 16777216);
  u16* bG  = (u16*)(ws + 4 * 16777216 + 2097152);

  cast_all<<<17920, 256, 0, stream>>>(y, x, Wr, Ur, Wz, Uz, Wg, Ug, yb, xb, bRZ, bG);
  gemm_rz3<<<256, 512, 0, stream>>>(yb, xb, bRZ, bg, rxb, zb);
  gemm_gu1<<<512, 256, 0, stream>>>(yb, rxb, bG, zb, xb, out);
}

// Round 4
// 203.425 us; speedup vs baseline: 1.0448x; 1.0322x over previous
//
#include <hip/hip_runtime.h>
#include <stdint.h>

typedef unsigned short u16;
typedef __attribute__((ext_vector_type(8))) __bf16 bf16x8;
typedef __attribute__((ext_vector_type(4))) float f32x4;

#define Dn 512
#define Mn 16384  // T*B rows

// ---------- helpers ----------

__device__ __forceinline__ u16 f2bf(float f) {
  unsigned u = __float_as_uint(f);
  u += 0x7fffu + ((u >> 16) & 1u);
  return (u16)(u >> 16);
}

__device__ __forceinline__ float bf2f(u16 b) {
  return __uint_as_float(((unsigned)b) << 16);
}

__device__ __forceinline__ void async16(const u16* g, u16* l) {
  // global -> LDS direct copy, 16 B per lane. LDS dest = wave-uniform base + lane*16.
  __builtin_amdgcn_global_load_lds(
      (const __attribute__((address_space(1))) unsigned int*)g,
      (__attribute__((address_space(3))) unsigned int*)l, 16, 0, 0);
}

__device__ __forceinline__ float sigmoidf_(float v) {
  return 1.f / (1.f + __expf(-v));
}

// ---------- merged cast kernel (grid-stride, 2048 blocks) ----------
// work items 0..16383: y/x rows -> yb/xb ; 16384..17919: 6 weights -> concat:
//   bRZ (1024 x 1024 bf16): rows 0-511 = [Wr | Ur], rows 512-1023 = [Wz | Uz]
//   bG  ( 512 x 1024 bf16): rows 0-511 = [Wg | Ug]
__global__ void cast_all2(const float* __restrict__ y, const float* __restrict__ x,
                          const float* w0, const float* w1, const float* w2,
                          const float* w3, const float* w4, const float* w5,
                          u16* __restrict__ yb, u16* __restrict__ xb,
                          u16* __restrict__ bRZ, u16* __restrict__ bG) {
  const int stride = gridDim.x * 256;
  for (int idx = blockIdx.x * 256 + (int)threadIdx.x; idx < 17920 * 256; idx += stride) {
    int b = idx >> 8;
    const int t = idx & 255;
    if (b < 16384) {
      const float* src;
      u16* dst;
      if (b < 8192) { src = y; dst = yb; }
      else          { src = x; dst = xb; b -= 8192; }
      const int i4 = b * 256 + t;
      float4 v = ((const float4*)src)[i4];
      ushort4 o;
      o.x = f2bf(v.x); o.y = f2bf(v.y); o.z = f2bf(v.z); o.w = f2bf(v.w);
      ((ushort4*)dst)[i4] = o;
      continue;
    }
    b -= 16384;
    const int wi = b >> 8;  // 0..5 : Wr,Ur,Wz,Uz,Wg,Ug
    const int bb = b & 255;
    const float* src = wi == 0 ? w0 : wi == 1 ? w1 : wi == 2 ? w2
                     : wi == 3 ? w3 : wi == 4 ? w4 : w5;
    const int i4 = bb * 256 + t;        // float4 index within 512x512 weight
    const int e  = i4 >> 7;             // output row 0..511
    const int c4 = i4 & 127;            // float4 col within 512
    float4 v = ((const float4*)src)[i4];
    ushort4 o;
    o.x = f2bf(v.x); o.y = f2bf(v.y); o.z = f2bf(v.z); o.w = f2bf(v.w);
    ushort4* base = (wi >= 4) ? (ushort4*)bG : (ushort4*)bRZ;
    const int row = e + ((wi == 2 || wi == 3) ? 512 : 0);
    const int off = row * 256 + c4 + ((wi & 1) ? 128 : 0);  // 256 ushort4 per 1024-col row
    base[off] = o;
  }
}

// ---------- GEMM 1: C = [y|x] @ bRZ^T  (M=16384, N=1024, K=1024) ----------
// 128x128 tile, BK=64, 32 KB LDS, grid 1024, 4 waves (2x2), wave 64x64.
// XCD-aware ordering: mb = blockIdx&127 (fast), nb = blockIdx>>7. Since 128%8==0,
// all 8 blocks sharing an A-slab get the same blockIdx%8 -> same XCD -> A staged
// from HBM once, served from that XCD's L2 for the other 7.
// XOR swizzle (0-conflict, proven): row r logical chunk c at phys c^(r&7).
// Epilogue: nb 0-3 -> rx = bf16(sigmoid(acc)*x); nb 4-7 -> z = bf16(sigmoid(acc-bg)).
__global__ __launch_bounds__(256, 4) void gemm_rz1(
    const u16* __restrict__ yb, const u16* __restrict__ xb,
    const u16* __restrict__ bRZ, const float* __restrict__ bg,
    u16* __restrict__ rxb, u16* __restrict__ zb) {
  __shared__ u16 smem[16384];  // sA 8192 | sB 8192 (u16), 32 KB
  u16* sA = smem;
  u16* sB = smem + 8192;

  const int tid = threadIdx.x;
  const int lane = tid & 63;
  const int wave = tid >> 6;
  const int waveM = wave >> 1, waveN = wave & 1;
  const int mb = blockIdx.x & 127, nb = blockIdx.x >> 7;  // mb fast -> A-sharers same XCD
  const int rowStart = mb * 128, colStart = nb * 128;
  const int wbyte = (tid & 192) * 16;
  const int lm = lane & 15, quad = lane >> 4;

  const int srow = tid >> 3;                              // 0..31 per slab
  const int scol = (((tid & 7) ^ ((tid >> 3) & 7)) * 8);  // logical chunk * 8 elems
  const int lswz = lm & 7;

  f32x4 acc[4][4] = {};

  for (int kq = 0; kq < 16; ++kq) {
    const int half = kq >> 3;
    const int k0 = (kq & 7) * 64;
    const u16* abase = half ? xb : yb;  // A = [y | x] along K
#pragma unroll
    for (int s = 0; s < 4; ++s) {
      async16(abase + (size_t)(rowStart + s * 32 + srow) * 512 + k0 + scol,
              (u16*)((char*)sA + s * 4096 + wbyte));
      async16(bRZ + (size_t)(colStart + s * 32 + srow) * 1024 + kq * 64 + scol,
              (u16*)((char*)sB + s * 4096 + wbyte));
    }
    __syncthreads();

#pragma unroll
    for (int kk = 0; kk < 2; ++kk) {
      bf16x8 aa[4], bw[4];
#pragma unroll
      for (int i = 0; i < 4; ++i)
        aa[i] = *(const bf16x8*)(sA + (waveM * 64 + i * 16 + lm) * 64 +
                                 ((kk * 4 + quad) ^ lswz) * 8);
#pragma unroll
      for (int j = 0; j < 4; ++j)
        bw[j] = *(const bf16x8*)(sB + (waveN * 64 + j * 16 + lm) * 64 +
                                 ((kk * 4 + quad) ^ lswz) * 8);
#pragma unroll
      for (int i = 0; i < 4; ++i)
#pragma unroll
        for (int j = 0; j < 4; ++j)
          acc[i][j] = __builtin_amdgcn_mfma_f32_16x16x32_bf16(aa[i], bw[j], acc[i][j], 0, 0, 0);
    }
    __syncthreads();
  }

  if (colStart < 512) {
    // R half: rx = bf16(sigmoid(acc) * x)
#pragma unroll
    for (int j = 0; j < 4; ++j) {
      const int e = colStart + waveN * 64 + j * 16 + lm;
#pragma unroll
      for (int i = 0; i < 4; ++i) {
        const int m0 = rowStart + waveM * 64 + i * 16 + quad * 4;
#pragma unroll
        for (int rg = 0; rg < 4; ++rg) {
          const size_t idx = (size_t)(m0 + rg) * 512 + e;
          const float r = sigmoidf_(acc[i][j][rg]);
          rxb[idx] = f2bf(r * bf2f(xb[idx]));
        }
      }
    }
  } else {
    // Z half: z = bf16(sigmoid(acc - bg))
#pragma unroll
    for (int j = 0; j < 4; ++j) {
      const int e = colStart - 512 + waveN * 64 + j * 16 + lm;
      const float bgv = bg[e];
#pragma unroll
      for (int i = 0; i < 4; ++i) {
        const int m0 = rowStart + waveM * 64 + i * 16 + quad * 4;
#pragma unroll
        for (int rg = 0; rg < 4; ++rg) {
          const size_t idx = (size_t)(m0 + rg) * 512 + e;
          zb[idx] = f2bf(sigmoidf_(acc[i][j][rg] - bgv));
        }
      }
    }
  }
}

// ---------- GEMM 2: accF = [y|rx] @ bG^T (M=16384, N=512, K=1024) ----------
// Re-tiled 64x128 (was 128x128): grid 256 mb x 4 nb = 1024 blocks -> 4 blocks/CU
// (gu1's 512 blocks = 2/CU was latency-bound: same per-block latency as rz1 with
// half the overlap). Same proven staging/swizzle primitives; A = 2 slabs, acc[2][4].
// mb fast, 256%8==0 -> A-sharers (4 nb) same XCD.
// Epilogue: out = (1-z)x + z*tanh(accF)
__global__ __launch_bounds__(256, 4) void gemm_gu2(
    const u16* __restrict__ yb, const u16* __restrict__ rxb,
    const u16* __restrict__ bG,
    const u16* __restrict__ zb, const u16* __restrict__ xb,
    float* __restrict__ out) {
  __shared__ u16 smem[12288];  // sA 64x64 (8KB) | sB 128x64 (16KB) = 24 KB
  u16* sA = smem;
  u16* sB = smem + 4096;

  const int tid = threadIdx.x;
  const int lane = tid & 63;
  const int wave = tid >> 6;
  const int waveM = wave >> 1, waveN = wave & 1;
  const int mb = blockIdx.x & 255, nb = blockIdx.x >> 8;  // mb fast -> A-sharers same XCD
  const int rowStart = mb * 64, colStart = nb * 128;
  const int wbyte = (tid & 192) * 16;  // wave*1024 B: each wave stages 8 rows x 64 cols
  const int lm = lane & 15, quad = lane >> 4;

  const int srow = tid >> 3;                              // 0..31 per slab
  const int scol = (((tid & 7) ^ ((tid >> 3) & 7)) * 8);  // pre-swizzled source chunk
  const int lswz = lm & 7;

  f32x4 acc[2][4] = {};

  for (int kq = 0; kq < 16; ++kq) {
    const int half = kq >> 3;
    const int k0 = (kq & 7) * 64;
    const u16* abase = half ? rxb : yb;  // A = [y | rx] along K
#pragma unroll
    for (int s = 0; s < 2; ++s)
      async16(abase + (size_t)(rowStart + s * 32 + srow) * 512 + k0 + scol,
              (u16*)((char*)sA + s * 4096 + wbyte));
#pragma unroll
    for (int s = 0; s < 4; ++s)
      async16(bG + (size_t)(colStart + s * 32 + srow) * 1024 + kq * 64 + scol,
              (u16*)((char*)sB + s * 4096 + wbyte));
    __syncthreads();

#pragma unroll
    for (int kk = 0; kk < 2; ++kk) {
      bf16x8 aa[2], bw[4];
#pragma unroll
      for (int i = 0; i < 2; ++i)
        aa[i] = *(const bf16x8*)(sA + (waveM * 32 + i * 16 + lm) * 64 +
                                 ((kk * 4 + quad) ^ lswz) * 8);
#pragma unroll
      for (int j = 0; j < 4; ++j)
        bw[j] = *(const bf16x8*)(sB + (waveN * 64 + j * 16 + lm) * 64 +
                                 ((kk * 4 + quad) ^ lswz) * 8);
#pragma unroll
      for (int i = 0; i < 2; ++i)
#pragma unroll
        for (int j = 0; j < 4; ++j)
          acc[i][j] = __builtin_amdgcn_mfma_f32_16x16x32_bf16(aa[i], bw[j], acc[i][j], 0, 0, 0);
    }
    __syncthreads();
  }

  // epilogue: out = (1-z)x + z*tanh(accF)
#pragma unroll
  for (int j = 0; j < 4; ++j) {
    const int e = colStart + waveN * 64 + j * 16 + lm;
#pragma unroll
    for (int i = 0; i < 2; ++i) {
      const int m0 = rowStart + waveM * 32 + i * 16 + quad * 4;
#pragma unroll
      for (int rg = 0; rg < 4; ++rg) {
        const size_t idx = (size_t)(m0 + rg) * 512 + e;
        const float pre = acc[i][j][rg];
        const float ex = __expf(-2.f * pre);
        const float h = (1.f - ex) / (1.f + ex);  // tanh
        const float z = bf2f(zb[idx]);
        const float xv = bf2f(xb[idx]);
        out[idx] = (1.f - z) * xv + z * h;
      }
    }
  }
}

// ---------- launch ----------
extern "C" void kernel_launch(void* const* d_in, const int* in_sizes, int n_in,
                              void* d_out, int out_size, void* d_ws, size_t ws_size,
                              hipStream_t stream) {
  const float* x  = (const float*)d_in[0];
  const float* y  = (const float*)d_in[1];
  const float* Wr = (const float*)d_in[2];
  const float* Ur = (const float*)d_in[3];
  const float* Wz = (const float*)d_in[4];
  const float* Uz = (const float*)d_in[5];
  const float* Wg = (const float*)d_in[6];
  const float* Ug = (const float*)d_in[7];
  const float* bg = (const float*)d_in[8];
  float* out = (float*)d_out;

  // ws layout (bytes): yb 16M | xb 16M | rxb 16M | zb 16M | bRZ 2M | bG 1M = 67 MB
  char* ws = (char*)d_ws;
  u16* yb  = (u16*)(ws);
  u16* xb  = (u16*)(ws + 16777216);
  u16* rxb = (u16*)(ws + 2 * 16777216);
  u16* zb  = (u16*)(ws + 3 * 16777216);
  u16* bRZ = (u16*)(ws + 4 * 16777216);
  u16* bG  = (u16*)(ws + 4 * 16777216 + 2097152);

  cast_all2<<<2048, 256, 0, stream>>>(y, x, Wr, Ur, Wz, Uz, Wg, Ug, yb, xb, bRZ, bG);
  gemm_rz1<<<1024, 256, 0, stream>>>(yb, xb, bRZ, bg, rxb, zb);
  gemm_gu2<<<1024, 256, 0, stream>>>(yb, rxb, bG, zb, xb, out);
}